// Round 1
// baseline (9118.571 us; speedup 1.0000x reference)
//
#include <hip/hip_runtime.h>

#define NB 32768
#define DD 16
#define HH 64
#define EPB 16
#define HP 68   // padded LDS row stride (floats): 16B-aligned rows, bank-conflict-free

struct Params {
  const float *ts, *x0;
  const float *W0,*b0,*g0,*gb0,*hb0;
  const float *W1,*b1,*g1,*gb1,*hb1;
  const float *W2,*b2,*g2,*gb2,*hb2;
  const float *W3,*b3,*g3,*gb3,*hb3;
  float *out;
};

__device__ __forceinline__ float sigm(float u){ return 1.0f/(1.0f+__expf(-u)); }
__device__ __forceinline__ float tanh_fast(float u){
  float au = fabsf(u);
  float e  = __expf(-2.0f*au);
  float t  = (1.0f-e)/(1.0f+e);
  return copysignf(t,u);
}

// One gated layer: 16 lanes per element, lane 'a' computes cols [4a..4a+3].
// h_out = tanh((h_in@W + b)*sigmoid(t*g+gb) + t*hb); s = sigmoid(..)*(1-h_out^2)
template<int DIN>
__device__ __forceinline__ void fwd_layer(
    const float* __restrict__ W, const float* __restrict__ bb,
    const float* __restrict__ g, const float* __restrict__ gb,
    const float* __restrict__ hb, float tcur,
    const float* inrow, float* outrow, float* srow, int a)
{
  const int j0 = a*4;
  float acc[4];
  #pragma unroll
  for(int r=0;r<4;++r) acc[r] = bb[j0+r];
  #pragma unroll
  for(int i=0;i<DIN;++i){
    const float hi = inrow[i];
    const float4 w = *reinterpret_cast<const float4*>(W + i*HH + j0);
    acc[0] += hi*w.x; acc[1] += hi*w.y; acc[2] += hi*w.z; acc[3] += hi*w.w;
  }
  #pragma unroll
  for(int r=0;r<4;++r){
    const int j = j0+r;
    const float gate = sigm(tcur*g[j]+gb[j]);
    const float pre  = acc[r]*gate + tcur*hb[j];
    const float th   = tanh_fast(pre);
    outrow[j] = th;
    srow[j]   = gate*(1.0f - th*th);
  }
}

__global__ __launch_bounds__(256,2) void traj_kernel(Params p){
  __shared__ float xbuf[EPB][DD];
  __shared__ float hA[EPB][HP];
  __shared__ float hB[EPB][HP];
  __shared__ float s0b[EPB][HP];
  __shared__ float s1b[EPB][HP];
  __shared__ float s2b[EPB][HP];
  __shared__ float twb[DD][HP];   // TW[a][k] = sig3[a]*W3[k][a], shared per block
  __shared__ float sig3b[DD];

  const int tid = threadIdx.x;
  const int e   = tid >> 4;      // element within block (0..15)
  const int a   = tid & 15;      // component / column-group / tangent row (0..15)
  const int b   = blockIdx.x * EPB + e;

  float zbx  = p.x0[b*DD + a];   // z base, x-component 'a'
  p.out[b*DD + a] = zbx;         // xs[0] = x0
  float zb16 = 0.f, zb17 = 0.f;  // log-det and 0.5*||dx||^2 integrals

  for(int step=0; step<2; ++step){
    const float t0 = p.ts[step];
    const float t1 = p.ts[step+1];
    const float hs = t1 - t0;
    float kx = 0.f, k16 = 0.f, k17 = 0.f;   // RK4 k accumulators
    float zwx = zbx;                         // stage input (x-component)

    for(int stage=0; stage<4; ++stage){
      const float cin  = (stage==0)?0.f:((stage==3)?1.f:0.5f);
      const float tcur = t0 + cin*hs;

      xbuf[e][a] = zwx;
      __syncthreads();

      // ---------------- forward pass (cooperative, 16 lanes/elem) ----------
      fwd_layer<DD>(p.W0,p.b0,p.g0,p.gb0,p.hb0,tcur,&xbuf[e][0],&hA[e][0],&s0b[e][0],a);
      __syncthreads();
      fwd_layer<HH>(p.W1,p.b1,p.g1,p.gb1,p.hb1,tcur,&hA[e][0],&hB[e][0],&s1b[e][0],a);
      __syncthreads();
      fwd_layer<HH>(p.W2,p.b2,p.g2,p.gb2,p.hb2,tcur,&hB[e][0],&hA[e][0],&s2b[e][0],a);
      __syncthreads();

      // layer 3 (no tanh): lane 'a' computes dx[a]
      float acc3 = p.b3[a];
      #pragma unroll
      for(int i=0;i<HH;++i) acc3 += hA[e][i]*p.W3[i*DD+a];
      const float gate3 = sigm(tcur*p.g3[a]+p.gb3[a]);
      const float dxk   = acc3*gate3 + tcur*p.hb3[a];
      if(e==0) sig3b[a] = gate3;
      __syncthreads();

      // TW[a][k] = sig3[a] * W3[k][a]  (t-dependent only; 4 entries/thread)
      {
        const float s3r = sig3b[e];
        const int k0 = a*4;
        #pragma unroll
        for(int q=0;q<4;++q) twb[e][k0+q] = s3r * p.W3[(k0+q)*DD + e];
      }
      __syncthreads();

      // ---------------- tangent row 'a': exact Jacobian-trace contribution --
      // V0[a,i] = W0[a,i]*s0[i]  (layer-0 matmul is free: V_{-1}=I)
      // V1 = (V0@W1)*s1 ; trace += sum_j (V1@W2)[a,j]*s2[j]*TW[a][j]
      float vn[HH];
      #pragma unroll
      for(int j=0;j<HH;++j) vn[j]=0.f;
      for(int ib=0; ib<4; ++ib){                 // rolled: W1 offset uniform
        float vi[16];
        #pragma unroll
        for(int ii=0; ii<16; ++ii){
          const int i = ib*16+ii;
          vi[ii] = p.W0[a*HH+i] * s0b[e][i];
        }
        #pragma unroll
        for(int ii=0; ii<16; ++ii){
          const float vv = vi[ii];
          const float* __restrict__ wr = p.W1 + (ib*16+ii)*HH;  // wave-uniform -> s_load
          #pragma unroll
          for(int j=0;j<HH;++j) vn[j] += vv*wr[j];
        }
      }
      #pragma unroll
      for(int j=0;j<HH;++j) vn[j] *= s1b[e][j];

      float tr = 0.f;
      for(int jb=0; jb<4; ++jb){                 // rolled: W2 offset uniform
        float acc[16];
        #pragma unroll
        for(int jj=0;jj<16;++jj) acc[jj]=0.f;
        #pragma unroll
        for(int i=0;i<HH;++i){
          const float vv = vn[i];
          const float* __restrict__ wr = p.W2 + i*HH + jb*16;   // wave-uniform -> s_load
          #pragma unroll
          for(int jj=0;jj<16;++jj) acc[jj] += vv*wr[jj];
        }
        const int jbase = jb*16;
        #pragma unroll
        for(int jj=0;jj<16;++jj)
          tr += acc[jj] * s2b[e][jbase+jj] * twb[a][jbase+jj];
      }
      #pragma unroll
      for(int m=8;m>=1;m>>=1) tr += __shfl_xor(tr, m, 16);   // sum 16 rows -> trace

      float sq = dxk*dxk;
      #pragma unroll
      for(int m=8;m>=1;m>>=1) sq += __shfl_xor(sq, m, 16);
      const float dv = 0.5f*sq;

      // ---------------- RK4 accumulate ----------------
      const float wg = (stage==0||stage==3)?1.f:2.f;
      kx  += wg*dxk;
      k16 += wg*tr;
      k17 += wg*dv;
      const float cn = (stage==2)?1.f:0.5f;
      if(stage<3) zwx = zbx + cn*hs*dxk;
    }
    zbx  += hs*(1.f/6.f)*kx;
    zb16 += hs*(1.f/6.f)*k16;
    zb17 += hs*(1.f/6.f)*k17;
    p.out[(step+1)*(NB*DD) + b*DD + a] = zbx;   // xs[step+1]
  }

  if(a==0){
    p.out[3*NB*DD + b]        = zb16;           // log_det
    p.out[3*NB*DD + NB + b]   = fabsf(zb17);    // loss_L
    p.out[3*NB*DD + 2*NB + b] = 0.f;            // zeros_like
  }
}

extern "C" void kernel_launch(void* const* d_in, const int* in_sizes, int n_in,
                              void* d_out, int out_size, void* d_ws, size_t ws_size,
                              hipStream_t stream){
  Params p;
  p.ts  = (const float*)d_in[0];
  p.x0  = (const float*)d_in[1];
  p.W0  = (const float*)d_in[2];  p.b0 =(const float*)d_in[3];
  p.g0  = (const float*)d_in[4];  p.gb0=(const float*)d_in[5];  p.hb0=(const float*)d_in[6];
  p.W1  = (const float*)d_in[7];  p.b1 =(const float*)d_in[8];
  p.g1  = (const float*)d_in[9];  p.gb1=(const float*)d_in[10]; p.hb1=(const float*)d_in[11];
  p.W2  = (const float*)d_in[12]; p.b2 =(const float*)d_in[13];
  p.g2  = (const float*)d_in[14]; p.gb2=(const float*)d_in[15]; p.hb2=(const float*)d_in[16];
  p.W3  = (const float*)d_in[17]; p.b3 =(const float*)d_in[18];
  p.g3  = (const float*)d_in[19]; p.gb3=(const float*)d_in[20]; p.hb3=(const float*)d_in[21];
  p.out = (float*)d_out;
  hipLaunchKernelGGL(traj_kernel, dim3(NB/EPB), dim3(256), 0, stream, p);
}

// Round 2
// 476.627 us; speedup vs baseline: 19.1314x; 19.1314x over previous
//
#include <hip/hip_runtime.h>

#define NB 32768
#define DD 16
#define HH 64
#define EPB 16

typedef __attribute__((ext_vector_type(8))) short short8;
typedef __attribute__((ext_vector_type(8))) unsigned short us8;
typedef __attribute__((ext_vector_type(4))) float f32x4;

struct Params {
  const float *ts, *x0;
  const float *W0,*b0,*g0,*gb0,*hb0;
  const float *W1,*b1,*g1,*gb1,*hb1;
  const float *W2,*b2,*g2,*gb2,*hb2;
  const float *W3,*b3,*g3,*gb3,*hb3;
  float *out;
};

__device__ __forceinline__ float bf2f(unsigned short u){
  union{unsigned u; float f;} t; t.u=((unsigned)u)<<16; return t.f;
}
__device__ __forceinline__ unsigned short f2bf(float f){
  union{float f; unsigned u;} t; t.f=f;
  unsigned r = t.u + 0x7FFFu + ((t.u>>16)&1u);   // RNE
  return (unsigned short)(r>>16);
}
__device__ __forceinline__ float sigm(float u){ return 1.0f/(1.0f+__expf(-u)); }
__device__ __forceinline__ float tanh_fast(float u){
  float au=fabsf(u), ee=__expf(-2.0f*au);
  float t=(1.0f-ee)/(1.0f+ee);
  return copysignf(t,u);
}
#define WV() __builtin_amdgcn_wave_barrier()

// gated layer, 16 lanes/element, lane 'a' computes cols [4a..4a+3]
// fp32 activations, bf16 weights from LDS
template<int DIN>
__device__ __forceinline__ void fwd_layer_b(
    const unsigned short (*Wb)[72], const float* __restrict__ bb,
    const float* __restrict__ g, const float* __restrict__ gb,
    const float* __restrict__ hb, float tcur,
    const float* inrow, float* outrow, unsigned short* srow, int a)
{
  const int j0=a*4;
  float acc0=bb[j0], acc1=bb[j0+1], acc2=bb[j0+2], acc3=bb[j0+3];
  #pragma unroll
  for(int i4=0;i4<DIN/4;++i4){
    const float4 h4 = *reinterpret_cast<const float4*>(inrow + i4*4);
    #pragma unroll
    for(int u=0;u<4;++u){
      const int i=i4*4+u;
      const float hi = (&h4.x)[u];
      const ushort4 w = *reinterpret_cast<const ushort4*>(&Wb[i][j0]);
      acc0 += hi*bf2f(w.x); acc1 += hi*bf2f(w.y);
      acc2 += hi*bf2f(w.z); acc3 += hi*bf2f(w.w);
    }
  }
  float accs[4]={acc0,acc1,acc2,acc3};
  #pragma unroll
  for(int r=0;r<4;++r){
    const int j=j0+r;
    const float gate=sigm(tcur*g[j]+gb[j]);
    const float pre =accs[r]*gate + tcur*hb[j];
    const float th  =tanh_fast(pre);
    outrow[j]=th;
    srow[j]=f2bf(gate*(1.0f-th*th));
  }
}

__global__ __launch_bounds__(256,2) void traj_kernel(Params p){
  // ---- LDS (~62 KB total -> 2 blocks/CU) ----
  __shared__ __align__(16) unsigned short w0b[DD][72];      // bf16 W0
  __shared__ __align__(16) unsigned short w1b[HH][72];      // bf16 W1 (fwd)
  __shared__ __align__(16) unsigned short w2b[HH][72];      // bf16 W2 (fwd)
  __shared__ __align__(16) unsigned short w3b[HH][18];      // bf16 W3 [i][a]
  __shared__ __align__(16) unsigned short w3t[DD][72];      // bf16 W3^T [a][j]
  __shared__ __align__(16) unsigned short w1f[2][4][64][8]; // W1 B-fragments
  __shared__ __align__(16) unsigned short w2f[2][4][64][8]; // W2 B-fragments
  __shared__ __align__(16) float xbuf[EPB][DD];
  __shared__ __align__(16) float hA[EPB][68];
  __shared__ __align__(16) unsigned short s0b[EPB][72];
  __shared__ __align__(16) unsigned short s1b[EPB][72];
  __shared__ __align__(16) unsigned short s2b[EPB][72];
  __shared__ float sig3w[4][DD];
  __shared__ __align__(16) unsigned short vtmp[4][16][72];  // per-wave V1 staging (also aliased as fwd hB)

  const int tid = threadIdx.x;
  const int e   = tid>>4;      // element in block (0..15)
  const int a   = tid&15;      // component / column group
  const int wv  = tid>>6;      // wave id (0..3)
  const int lane= tid&63;
  const int m   = lane&15;     // MFMA row / col index
  const int q   = lane>>4;     // MFMA quad
  const int b   = blockIdx.x*EPB + e;

  // ---- one-time weight staging ----
  for(int idx=tid; idx<DD*HH; idx+=256) w0b[idx>>6][idx&63]=f2bf(p.W0[idx]);
  for(int idx=tid; idx<HH*HH; idx+=256){
    w1b[idx>>6][idx&63]=f2bf(p.W1[idx]);
    w2b[idx>>6][idx&63]=f2bf(p.W2[idx]);
  }
  for(int idx=tid; idx<HH*DD; idx+=256){
    unsigned short v=f2bf(p.W3[idx]);
    w3b[idx>>4][idx&15]=v; w3t[idx&15][idx>>4]=v;
  }
  for(int idx=tid; idx<4096; idx+=256){
    const int j=idx&7, ln=(idx>>3)&63, nt=(idx>>9)&3, kk=idx>>11;
    const int k=kk*32+(ln>>4)*8+j, n=nt*16+(ln&15);
    w1f[kk][nt][ln][j]=f2bf(p.W1[k*HH+n]);
    w2f[kk][nt][ln][j]=f2bf(p.W2[k*HH+n]);
  }
  __syncthreads();   // the only block barrier

  float zbx = p.x0[b*DD+a];
  p.out[b*DD+a]=zbx;
  float zb16=0.f, zb17=0.f;

  #pragma unroll 1
  for(int step=0; step<2; ++step){
    const float t0=p.ts[step], t1=p.ts[step+1];
    const float hs=t1-t0;
    float kx=0.f,k16=0.f,k17=0.f;
    float zwx=zbx;
    #pragma unroll 1
    for(int stage=0; stage<4; ++stage){
      const float cin=(stage==0)?0.f:((stage==3)?1.f:0.5f);
      const float tcur=t0+cin*hs;

      xbuf[e][a]=zwx; WV();

      // ---------------- forward (fp32 act, bf16 weights) ----------------
      fwd_layer_b<DD>(w0b,p.b0,p.g0,p.gb0,p.hb0,tcur,&xbuf[e][0],&hA[e][0],&s0b[e][0],a); WV();
      float* hB = reinterpret_cast<float*>(vtmp[wv]) + (e&3)*72;
      fwd_layer_b<HH>(w1b,p.b1,p.g1,p.gb1,p.hb1,tcur,&hA[e][0],hB,&s1b[e][0],a); WV();
      fwd_layer_b<HH>(w2b,p.b2,p.g2,p.gb2,p.hb2,tcur,hB,&hA[e][0],&s2b[e][0],a); WV();
      float acc3v=p.b3[a];
      #pragma unroll
      for(int i4=0;i4<HH/4;++i4){
        const float4 h4=*reinterpret_cast<const float4*>(&hA[e][i4*4]);
        acc3v += h4.x*bf2f(w3b[i4*4+0][a]);
        acc3v += h4.y*bf2f(w3b[i4*4+1][a]);
        acc3v += h4.z*bf2f(w3b[i4*4+2][a]);
        acc3v += h4.w*bf2f(w3b[i4*4+3][a]);
      }
      const float gate3=sigm(tcur*p.g3[a]+p.gb3[a]);
      const float dxk=acc3v*gate3+tcur*p.hb3[a];
      sig3w[wv][a]=gate3;             // same value from all 4 e-groups: benign
      float sq=dxk*dxk;
      #pragma unroll
      for(int mk=8;mk>=1;mk>>=1) sq+=__shfl_xor(sq,mk,16);
      const float dv=0.5f*sq;
      WV();

      // ---------------- tangent: MFMA per element of this wave ----------
      float trloc=0.f;
      #pragma unroll 1
      for(int el=0; el<4; ++el){
        const int ee=wv*4+el;
        // A0[m][k] = W0[m][k]*s0[k]  (bf16)
        short8 a0[2];
        #pragma unroll
        for(int kk=0;kk<2;++kk){
          const int k0=kk*32+q*8;
          const us8 w8=*reinterpret_cast<const us8*>(&w0b[m][k0]);
          const us8 s8=*reinterpret_cast<const us8*>(&s0b[ee][k0]);
          short8 t;
          #pragma unroll
          for(int j=0;j<8;++j) t[j]=(short)f2bf(bf2f(w8[j])*bf2f(s8[j]));
          a0[kk]=t;
        }
        // GEMM1: V1pre = A0 @ W1
        f32x4 c1[4] = {};
        #pragma unroll
        for(int kk=0;kk<2;++kk){
          #pragma unroll
          for(int nt=0;nt<4;++nt){
            const short8 bfr=*reinterpret_cast<const short8*>(&w1f[kk][nt][lane][0]);
            c1[nt]=__builtin_amdgcn_mfma_f32_16x16x32_bf16(a0[kk],bfr,c1[nt],0,0,0);
          }
        }
        // scale by s1, stage to LDS in A-layout source form
        #pragma unroll
        for(int nt=0;nt<4;++nt){
          const float sc=bf2f(s1b[ee][nt*16+m]);
          #pragma unroll
          for(int r=0;r<4;++r)
            vtmp[wv][q*4+r][nt*16+m]=f2bf(c1[nt][r]*sc);  // D: row=q*4+r, col=nt*16+m
        }
        WV();
        short8 a2[2];
        #pragma unroll
        for(int kk=0;kk<2;++kk)
          a2[kk]=*reinterpret_cast<const short8*>(&vtmp[wv][m][kk*32+q*8]);
        // GEMM2: V2 = V1 @ W2
        f32x4 c2[4] = {};
        #pragma unroll
        for(int kk=0;kk<2;++kk){
          #pragma unroll
          for(int nt=0;nt<4;++nt){
            const short8 bfr=*reinterpret_cast<const short8*>(&w2f[kk][nt][lane][0]);
            c2[nt]=__builtin_amdgcn_mfma_f32_16x16x32_bf16(a2[kk],bfr,c2[nt],0,0,0);
          }
        }
        // trace = sum V2[row][j]*s2[j]*sig3[row]*W3[j][row]
        const float sg0=sig3w[wv][q*4+0], sg1=sig3w[wv][q*4+1],
                    sg2=sig3w[wv][q*4+2], sg3v=sig3w[wv][q*4+3];
        float tr=0.f;
        #pragma unroll
        for(int nt=0;nt<4;++nt){
          const int j=nt*16+m;
          const float s2v=bf2f(s2b[ee][j]);
          tr += c2[nt][0]*s2v*sg0 *bf2f(w3t[q*4+0][j]);
          tr += c2[nt][1]*s2v*sg1 *bf2f(w3t[q*4+1][j]);
          tr += c2[nt][2]*s2v*sg2 *bf2f(w3t[q*4+2][j]);
          tr += c2[nt][3]*s2v*sg3v*bf2f(w3t[q*4+3][j]);
        }
        #pragma unroll
        for(int mk=32;mk>=1;mk>>=1) tr+=__shfl_xor(tr,mk,64);
        if(e==ee) trloc=tr;
        WV();   // vtmp reused next el
      }

      // ---------------- RK4 accumulate ----------------
      const float wg=(stage==0||stage==3)?1.f:2.f;
      kx+=wg*dxk; k16+=wg*trloc; k17+=wg*dv;
      const float cn=(stage==2)?1.f:0.5f;
      if(stage<3) zwx=zbx+cn*hs*dxk;
    }
    zbx +=hs*(1.f/6.f)*kx;
    zb16+=hs*(1.f/6.f)*k16;
    zb17+=hs*(1.f/6.f)*k17;
    p.out[(step+1)*(NB*DD)+b*DD+a]=zbx;
  }

  if(a==0){
    p.out[3*NB*DD+b]        =zb16;
    p.out[3*NB*DD+NB+b]     =fabsf(zb17);
    p.out[3*NB*DD+2*NB+b]   =0.f;
  }
}

extern "C" void kernel_launch(void* const* d_in, const int* in_sizes, int n_in,
                              void* d_out, int out_size, void* d_ws, size_t ws_size,
                              hipStream_t stream){
  Params p;
  p.ts  = (const float*)d_in[0];
  p.x0  = (const float*)d_in[1];
  p.W0  = (const float*)d_in[2];  p.b0 =(const float*)d_in[3];
  p.g0  = (const float*)d_in[4];  p.gb0=(const float*)d_in[5];  p.hb0=(const float*)d_in[6];
  p.W1  = (const float*)d_in[7];  p.b1 =(const float*)d_in[8];
  p.g1  = (const float*)d_in[9];  p.gb1=(const float*)d_in[10]; p.hb1=(const float*)d_in[11];
  p.W2  = (const float*)d_in[12]; p.b2 =(const float*)d_in[13];
  p.g2  = (const float*)d_in[14]; p.gb2=(const float*)d_in[15]; p.hb2=(const float*)d_in[16];
  p.W3  = (const float*)d_in[17]; p.b3 =(const float*)d_in[18];
  p.g3  = (const float*)d_in[19]; p.gb3=(const float*)d_in[20]; p.hb3=(const float*)d_in[21];
  p.out = (float*)d_out;
  hipLaunchKernelGGL(traj_kernel, dim3(NB/EPB), dim3(256), 0, stream, p);
}

// Round 3
// 348.915 us; speedup vs baseline: 26.1340x; 1.3660x over previous
//
#include <hip/hip_runtime.h>

#define NB 32768
#define DD 16
#define HH 64
#define EPB 16

typedef __attribute__((ext_vector_type(8))) short short8;
typedef __attribute__((ext_vector_type(8))) unsigned short us8;
typedef __attribute__((ext_vector_type(4))) float f32x4;

struct Params {
  const float *ts, *x0;
  const float *W0,*b0,*g0,*gb0,*hb0;
  const float *W1,*b1,*g1,*gb1,*hb1;
  const float *W2,*b2,*g2,*gb2,*hb2;
  const float *W3,*b3,*g3,*gb3,*hb3;
  float *out;
};

__device__ __forceinline__ float bf2f(unsigned short u){
  union{unsigned u; float f;} t; t.u=((unsigned)u)<<16; return t.f;
}
__device__ __forceinline__ unsigned short f2bf(float f){
  union{float f; unsigned u;} t; t.f=f;
  unsigned r = t.u + 0x7FFFu + ((t.u>>16)&1u);   // RNE
  return (unsigned short)(r>>16);
}
__device__ __forceinline__ float sigm(float u){ return 1.0f/(1.0f+__expf(-u)); }
__device__ __forceinline__ float tanh_fast(float u){
  float au=fabsf(u), ee=__expf(-2.0f*au);
  float t=(1.0f-ee)/(1.0f+ee);
  return copysignf(t,u);
}
#define WV() __builtin_amdgcn_wave_barrier()
#define MFMA(A,B,C) __builtin_amdgcn_mfma_f32_16x16x32_bf16((A),(B),(C),0,0,0)

__global__ __launch_bounds__(256,2) void traj_kernel(Params p){
  // ---- LDS (~35 KB) ----
  __shared__ __align__(16) unsigned short w0b[DD][72];   // W0[a][i] (tangent A0 source)
  __shared__ __align__(16) unsigned short w3t[DD][72];   // W3^T[a][j] (trace epilogue)
  __shared__ __align__(16) float xbuf[DD][20];           // fp32 state x
  __shared__ __align__(16) unsigned short hbh[2][EPB][72]; // activation hi, ping-pong
  __shared__ __align__(16) unsigned short hbl[2][EPB][72]; // activation lo
  __shared__ __align__(16) unsigned short sb[3][EPB][72];  // s0,s1,s2
  __shared__ float dxw[4][EPB][17];                      // per-wave dx (fp32)
  __shared__ float sig3w[4][DD];
  __shared__ __align__(16) unsigned short vt[4][DD][72]; // per-wave V1 staging

  const int tid = threadIdx.x;
  const int e   = tid>>4;      // element (0..15)
  const int a   = tid&15;      // component / col
  const int wv  = tid>>6;      // wave (0..3)
  const int lane= tid&63;
  const int m   = lane&15;     // MFMA col / A-row
  const int q   = lane>>4;     // MFMA quad
  const int b   = blockIdx.x*EPB + e;
  const int jw  = wv*16 + m;   // this wave's fwd output column

  // ---- persistent register weight fragments (B-operand layout) ----
  short8 f0fr, f1fr[2], f2fr[2];       // fwd: only this wave's nt=wv columns
  short8 b1fr[2][4], b2fr[2][4], b3fr[2];
  {
    #pragma unroll
    for(int j=0;j<8;++j){
      const int k=q*8+j;
      f0fr[j] = (k<DD) ? (short)f2bf(p.W0[k*HH+jw]) : (short)0;
    }
    #pragma unroll
    for(int kk=0;kk<2;++kk){
      #pragma unroll
      for(int j=0;j<8;++j){
        const int k=kk*32+q*8+j;
        f1fr[kk][j]=(short)f2bf(p.W1[k*HH+jw]);
        f2fr[kk][j]=(short)f2bf(p.W2[k*HH+jw]);
        b3fr[kk][j]=(short)f2bf(p.W3[k*DD+m]);
      }
      #pragma unroll
      for(int nt=0;nt<4;++nt){
        #pragma unroll
        for(int j=0;j<8;++j){
          const int k=kk*32+q*8+j;
          b1fr[kk][nt][j]=(short)f2bf(p.W1[k*HH+nt*16+m]);
          b2fr[kk][nt][j]=(short)f2bf(p.W2[k*HH+nt*16+m]);
        }
      }
    }
  }
  // bias/gate scalars for this lane's columns (t-independent parts)
  const float bc0=p.b0[jw], gc0=p.g0[jw], gbc0=p.gb0[jw], hbc0=p.hb0[jw];
  const float bc1=p.b1[jw], gc1=p.g1[jw], gbc1=p.gb1[jw], hbc1=p.hb1[jw];
  const float bc2=p.b2[jw], gc2=p.g2[jw], gbc2=p.gb2[jw], hbc2=p.hb2[jw];
  const float bc3=p.b3[m],  gc3=p.g3[m],  gbc3=p.gb3[m],  hbc3=p.hb3[m];

  // ---- one-time LDS staging ----
  for(int idx=tid; idx<DD*HH; idx+=256) w0b[idx>>6][idx&63]=f2bf(p.W0[idx]);
  for(int idx=tid; idx<HH*DD; idx+=256) w3t[idx&15][idx>>4]=f2bf(p.W3[idx]);
  __syncthreads();

  float zbx = p.x0[b*DD+a];
  p.out[b*DD+a]=zbx;
  float zb16=0.f, zb17=0.f;

  #pragma unroll 1
  for(int step=0; step<2; ++step){
    const float t0=p.ts[step], t1=p.ts[step+1];
    const float hs=t1-t0;
    float kx=0.f,k16=0.f,k17=0.f;
    float zwx=zbx;
    #pragma unroll 1
    for(int stage=0; stage<4; ++stage){
      const float cin=(stage==0)?0.f:((stage==3)?1.f:0.5f);
      const float tcur=t0+cin*hs;

      xbuf[e][a]=zwx;
      __syncthreads();                       // B1

      // ---------- L0: pre = X @ W0 (hi/lo split, K=16 zero-padded) ----------
      f32x4 c={0.f,0.f,0.f,0.f};
      {
        short8 xhi={0,0,0,0,0,0,0,0}, xlo={0,0,0,0,0,0,0,0};
        if(q<2){
          const float* xr=&xbuf[m][q*8];
          #pragma unroll
          for(int j=0;j<8;++j){
            const float xv=xr[j];
            const unsigned short h1=f2bf(xv);
            xhi[j]=(short)h1;
            xlo[j]=(short)f2bf(xv-bf2f(h1));
          }
        }
        c=MFMA(xhi,f0fr,c); c=MFMA(xlo,f0fr,c);
      }
      {
        const float gate=sigm(tcur*gc0+gbc0);
        const float tb=tcur*hbc0;
        #pragma unroll
        for(int r=0;r<4;++r){
          const int el=q*4+r;
          const float pre=(c[r]+bc0)*gate+tb;
          const float th=tanh_fast(pre);
          const unsigned short hi=f2bf(th);
          hbh[0][el][jw]=hi;
          hbl[0][el][jw]=f2bf(th-bf2f(hi));
          sb[0][el][jw]=f2bf(gate*(1.f-th*th));
        }
      }
      __syncthreads();                       // B2

      // ---------- L1: h0 @ W1 ----------
      c[0]=0.f;c[1]=0.f;c[2]=0.f;c[3]=0.f;
      #pragma unroll
      for(int kk=0;kk<2;++kk){
        const short8 ah=*reinterpret_cast<const short8*>(&hbh[0][m][kk*32+q*8]);
        const short8 al=*reinterpret_cast<const short8*>(&hbl[0][m][kk*32+q*8]);
        c=MFMA(ah,f1fr[kk],c); c=MFMA(al,f1fr[kk],c);
      }
      {
        const float gate=sigm(tcur*gc1+gbc1);
        const float tb=tcur*hbc1;
        #pragma unroll
        for(int r=0;r<4;++r){
          const int el=q*4+r;
          const float pre=(c[r]+bc1)*gate+tb;
          const float th=tanh_fast(pre);
          const unsigned short hi=f2bf(th);
          hbh[1][el][jw]=hi;
          hbl[1][el][jw]=f2bf(th-bf2f(hi));
          sb[1][el][jw]=f2bf(gate*(1.f-th*th));
        }
      }
      __syncthreads();                       // B3

      // ---------- L2: h1 @ W2 ----------
      c[0]=0.f;c[1]=0.f;c[2]=0.f;c[3]=0.f;
      #pragma unroll
      for(int kk=0;kk<2;++kk){
        const short8 ah=*reinterpret_cast<const short8*>(&hbh[1][m][kk*32+q*8]);
        const short8 al=*reinterpret_cast<const short8*>(&hbl[1][m][kk*32+q*8]);
        c=MFMA(ah,f2fr[kk],c); c=MFMA(al,f2fr[kk],c);
      }
      {
        const float gate=sigm(tcur*gc2+gbc2);
        const float tb=tcur*hbc2;
        #pragma unroll
        for(int r=0;r<4;++r){
          const int el=q*4+r;
          const float pre=(c[r]+bc2)*gate+tb;
          const float th=tanh_fast(pre);
          const unsigned short hi=f2bf(th);
          hbh[0][el][jw]=hi;                 // h2 -> buffer 0 (safe: h0 dead)
          hbl[0][el][jw]=f2bf(th-bf2f(hi));
          sb[2][el][jw]=f2bf(gate*(1.f-th*th));
        }
      }
      __syncthreads();                       // B4

      // ---------- L3: dx = (h2 @ W3 + b3)*gate3 + t*hb3 (all waves) ----------
      c[0]=0.f;c[1]=0.f;c[2]=0.f;c[3]=0.f;
      #pragma unroll
      for(int kk=0;kk<2;++kk){
        const short8 ah=*reinterpret_cast<const short8*>(&hbh[0][m][kk*32+q*8]);
        const short8 al=*reinterpret_cast<const short8*>(&hbl[0][m][kk*32+q*8]);
        c=MFMA(ah,b3fr[kk],c); c=MFMA(al,b3fr[kk],c);
      }
      const float gate3=sigm(tcur*gc3+gbc3);
      {
        const float tb=tcur*hbc3;
        #pragma unroll
        for(int r=0;r<4;++r)
          dxw[wv][q*4+r][m]=(c[r]+bc3)*gate3+tb;
        if(q==0) sig3w[wv][m]=gate3;
      }
      WV();
      const float dxk=dxw[wv][e][a];
      float sq=dxk*dxk;
      #pragma unroll
      for(int mk=8;mk>=1;mk>>=1) sq+=__shfl_xor(sq,mk,16);
      const float dv=0.5f*sq;

      // ---------- tangent: exact Jacobian trace via MFMA (per wave's 4 els) --
      float trloc=0.f;
      #pragma unroll 1
      for(int el4=0; el4<4; ++el4){
        const int ee=wv*4+el4;
        short8 a0[2];
        #pragma unroll
        for(int kk=0;kk<2;++kk){
          const int k0=kk*32+q*8;
          const us8 w8=*reinterpret_cast<const us8*>(&w0b[m][k0]);
          const us8 s8=*reinterpret_cast<const us8*>(&sb[0][ee][k0]);
          short8 t;
          #pragma unroll
          for(int j=0;j<8;++j) t[j]=(short)f2bf(bf2f(w8[j])*bf2f(s8[j]));
          a0[kk]=t;
        }
        f32x4 c1[4]={{0.f,0.f,0.f,0.f},{0.f,0.f,0.f,0.f},{0.f,0.f,0.f,0.f},{0.f,0.f,0.f,0.f}};
        #pragma unroll
        for(int kk=0;kk<2;++kk){
          #pragma unroll
          for(int nt=0;nt<4;++nt)
            c1[nt]=MFMA(a0[kk],b1fr[kk][nt],c1[nt]);
        }
        #pragma unroll
        for(int nt=0;nt<4;++nt){
          const float sc=bf2f(sb[1][ee][nt*16+m]);
          #pragma unroll
          for(int r=0;r<4;++r)
            vt[wv][q*4+r][nt*16+m]=f2bf(c1[nt][r]*sc);
        }
        WV();
        short8 a2[2];
        #pragma unroll
        for(int kk=0;kk<2;++kk)
          a2[kk]=*reinterpret_cast<const short8*>(&vt[wv][m][kk*32+q*8]);
        f32x4 c2[4]={{0.f,0.f,0.f,0.f},{0.f,0.f,0.f,0.f},{0.f,0.f,0.f,0.f},{0.f,0.f,0.f,0.f}};
        #pragma unroll
        for(int kk=0;kk<2;++kk){
          #pragma unroll
          for(int nt=0;nt<4;++nt)
            c2[nt]=MFMA(a2[kk],b2fr[kk][nt],c2[nt]);
        }
        const float sg0=sig3w[wv][q*4+0], sg1=sig3w[wv][q*4+1],
                    sg2=sig3w[wv][q*4+2], sg3v=sig3w[wv][q*4+3];
        float tr=0.f;
        #pragma unroll
        for(int nt=0;nt<4;++nt){
          const int j=nt*16+m;
          const float s2v=bf2f(sb[2][ee][j]);
          tr += c2[nt][0]*s2v*sg0 *bf2f(w3t[q*4+0][j]);
          tr += c2[nt][1]*s2v*sg1 *bf2f(w3t[q*4+1][j]);
          tr += c2[nt][2]*s2v*sg2 *bf2f(w3t[q*4+2][j]);
          tr += c2[nt][3]*s2v*sg3v*bf2f(w3t[q*4+3][j]);
        }
        #pragma unroll
        for(int mk=32;mk>=1;mk>>=1) tr+=__shfl_xor(tr,mk,64);
        if(e==ee) trloc=tr;
        WV();
      }

      // ---------- RK4 accumulate ----------
      const float wg=(stage==0||stage==3)?1.f:2.f;
      kx+=wg*dxk; k16+=wg*trloc; k17+=wg*dv;
      const float cn=(stage==2)?1.f:0.5f;
      if(stage<3) zwx=zbx+cn*hs*dxk;
    }
    zbx +=hs*(1.f/6.f)*kx;
    zb16+=hs*(1.f/6.f)*k16;
    zb17+=hs*(1.f/6.f)*k17;
    p.out[(step+1)*(NB*DD)+b*DD+a]=zbx;
  }

  if(a==0){
    p.out[3*NB*DD+b]        =zb16;
    p.out[3*NB*DD+NB+b]     =fabsf(zb17);
    p.out[3*NB*DD+2*NB+b]   =0.f;
  }
}

extern "C" void kernel_launch(void* const* d_in, const int* in_sizes, int n_in,
                              void* d_out, int out_size, void* d_ws, size_t ws_size,
                              hipStream_t stream){
  Params p;
  p.ts  = (const float*)d_in[0];
  p.x0  = (const float*)d_in[1];
  p.W0  = (const float*)d_in[2];  p.b0 =(const float*)d_in[3];
  p.g0  = (const float*)d_in[4];  p.gb0=(const float*)d_in[5];  p.hb0=(const float*)d_in[6];
  p.W1  = (const float*)d_in[7];  p.b1 =(const float*)d_in[8];
  p.g1  = (const float*)d_in[9];  p.gb1=(const float*)d_in[10]; p.hb1=(const float*)d_in[11];
  p.W2  = (const float*)d_in[12]; p.b2 =(const float*)d_in[13];
  p.g2  = (const float*)d_in[14]; p.gb2=(const float*)d_in[15]; p.hb2=(const float*)d_in[16];
  p.W3  = (const float*)d_in[17]; p.b3 =(const float*)d_in[18];
  p.g3  = (const float*)d_in[19]; p.gb3=(const float*)d_in[20]; p.hb3=(const float*)d_in[21];
  p.out = (float*)d_out;
  hipLaunchKernelGGL(traj_kernel, dim3(NB/EPB), dim3(256), 0, stream, p);
}

// Round 4
// 265.858 us; speedup vs baseline: 34.2987x; 1.3124x over previous
//
#include <hip/hip_runtime.h>

#define NB 32768
#define DD 16
#define HH 64
#define EPB 16

typedef __attribute__((ext_vector_type(8))) short short8;
typedef __attribute__((ext_vector_type(4))) float f32x4;
typedef __attribute__((ext_vector_type(4))) unsigned uint4v;

union Frag { short8 s; uint4v u; unsigned d[4]; };

struct Params {
  const float *ts, *x0;
  const float *W0,*b0,*g0,*gb0,*hb0;
  const float *W1,*b1,*g1,*gb1,*hb1;
  const float *W2,*b2,*g2,*gb2,*hb2;
  const float *W3,*b3,*g3,*gb3,*hb3;
  float *out;
};

__device__ __forceinline__ float bfs(unsigned short u){   // bf16 -> f32
  return __uint_as_float(((unsigned)u)<<16);
}
__device__ __forceinline__ unsigned short f2bf(float f){  // full RNE (init only)
  unsigned u=__float_as_uint(f);
  return (unsigned short)((u + 0x7FFFu + ((u>>16)&1u))>>16);
}
// round-to-nearest (ties-away) bf16, packed pair: 3 ops / 2 values
__device__ __forceinline__ unsigned pk2bf(float lo, float hi){
  unsigned a=__float_as_uint(lo)+0x8000u;
  unsigned b=__float_as_uint(hi)+0x8000u;
  return __builtin_amdgcn_perm(b, a, 0x07060302u);   // {hi16(b),hi16(a)}
}
__device__ __forceinline__ unsigned short f2bf1(float f){  // single, 2 ops
  return (unsigned short)((__float_as_uint(f)+0x8000u)>>16);
}
__device__ __forceinline__ float sigm(float u){
  return __builtin_amdgcn_rcpf(1.0f+__builtin_amdgcn_exp2f(-1.44269504f*u));
}
__device__ __forceinline__ float tanh_fast(float u){
  float au=fabsf(u);
  float e=__builtin_amdgcn_exp2f(-2.88539008f*au);
  float t=(1.0f-e)*__builtin_amdgcn_rcpf(1.0f+e);
  return copysignf(t,u);
}
#define WV() __builtin_amdgcn_wave_barrier()
#define MFMA(A,B,C) __builtin_amdgcn_mfma_f32_16x16x32_bf16((A),(B),(C),0,0,0)

__global__ __launch_bounds__(256,2) void traj_kernel(Params p){
  __shared__ __align__(16) unsigned short w0b[DD][72];     // W0[a][i]
  __shared__ __align__(16) unsigned short w3t[DD][72];     // W3^T[a][j]
  __shared__ __align__(16) float xbuf[DD][20];
  __shared__ __align__(16) unsigned short hbh[2][EPB][72]; // act hi
  __shared__ __align__(16) unsigned short hbl[2][EPB][72]; // act lo
  __shared__ __align__(16) unsigned short sb[3][EPB][72];  // s0,s1,s2
  __shared__ float dxw[4][EPB][17];
  __shared__ __align__(16) float sig3w[4][DD];
  __shared__ __align__(16) unsigned short vt[4][DD][72];   // per-wave V1

  const int tid = threadIdx.x;
  const int e   = tid>>4;
  const int a   = tid&15;
  const int wv  = tid>>6;
  const int lane= tid&63;
  const int m   = lane&15;
  const int q   = lane>>4;
  const int b   = blockIdx.x*EPB + e;
  const int jw  = wv*16 + m;     // forward output column of this lane

  // ---- persistent register weight fragments ----
  // fwd B-frags (cols jw):
  short8 f0fr, f1fr[2], f2fr[2], b3fr[2];
  // tangent B-frags, N-PERMUTED: slot (kk,nt,j) holds W[k][4m+nt]
  short8 b1fr[2][4], b2fr[2][4];
  {
    #pragma unroll
    for(int j=0;j<8;++j){
      const int k=q*8+j;
      f0fr[j]=(k<DD)?(short)f2bf(p.W0[k*HH+jw]):(short)0;
    }
    #pragma unroll
    for(int kk=0;kk<2;++kk){
      #pragma unroll
      for(int j=0;j<8;++j){
        const int k=kk*32+q*8+j;
        f1fr[kk][j]=(short)f2bf(p.W1[k*HH+jw]);
        f2fr[kk][j]=(short)f2bf(p.W2[k*HH+jw]);
        b3fr[kk][j]=(short)f2bf(p.W3[k*DD+m]);
      }
      #pragma unroll
      for(int nt=0;nt<4;++nt){
        #pragma unroll
        for(int j=0;j<8;++j){
          const int k=kk*32+q*8+j;
          b1fr[kk][nt][j]=(short)f2bf(p.W1[k*HH+4*m+nt]);
          b2fr[kk][nt][j]=(short)f2bf(p.W2[k*HH+4*m+nt]);
        }
      }
    }
  }
  const float bc0=p.b0[jw], gc0=p.g0[jw], gbc0=p.gb0[jw], hbc0=p.hb0[jw];
  const float bc1=p.b1[jw], gc1=p.g1[jw], gbc1=p.gb1[jw], hbc1=p.hb1[jw];
  const float bc2=p.b2[jw], gc2=p.g2[jw], gbc2=p.gb2[jw], hbc2=p.hb2[jw];
  const float bc3=p.b3[m],  gc3=p.g3[m],  gbc3=p.gb3[m],  hbc3=p.hb3[m];

  for(int idx=tid; idx<DD*HH; idx+=256) w0b[idx>>6][idx&63]=f2bf(p.W0[idx]);
  for(int idx=tid; idx<HH*DD; idx+=256) w3t[idx&15][idx>>4]=f2bf(p.W3[idx]);
  __syncthreads();

  float zbx = p.x0[b*DD+a];
  p.out[b*DD+a]=zbx;
  float trp[4]={0.f,0.f,0.f,0.f};   // deferred log-det partials (this wave's 4 els)
  float dvp=0.f;                     // deferred loss partial (this thread)

  #pragma unroll 1
  for(int step=0; step<2; ++step){
    const float t0=p.ts[step], t1=p.ts[step+1];
    const float hs=t1-t0;
    float dzx=0.f;
    float zwx=zbx;
    #pragma unroll 1
    for(int stage=0; stage<4; ++stage){
      const float cin=(stage==0)?0.f:((stage==3)?1.f:0.5f);
      const float tcur=t0+cin*hs;
      const float wg=(stage==0||stage==3)?1.f:2.f;
      const float fs=hs*(1.f/6.f)*wg;

      xbuf[e][a]=zwx;
      __syncthreads();                       // B1

      // ---------- L0: X @ W0 (hi/lo split) ----------
      f32x4 c={bc0,bc0,bc0,bc0};
      {
        Frag xh, xl; xh.s=short8{0,0,0,0,0,0,0,0}; xl.s=xh.s;
        if(q<2){
          const float4 xa=*reinterpret_cast<const float4*>(&xbuf[m][q*8]);
          const float4 xb=*reinterpret_cast<const float4*>(&xbuf[m][q*8+4]);
          const float xv[8]={xa.x,xa.y,xa.z,xa.w,xb.x,xb.y,xb.z,xb.w};
          #pragma unroll
          for(int d=0;d<4;++d){
            const unsigned u0=__float_as_uint(xv[2*d]), u1=__float_as_uint(xv[2*d+1]);
            xh.d[d]=__builtin_amdgcn_perm(u1,u0,0x07060302u);   // trunc hi
            const float l0=xv[2*d]-__uint_as_float(u0&0xFFFF0000u);
            const float l1=xv[2*d+1]-__uint_as_float(u1&0xFFFF0000u);
            xl.d[d]=pk2bf(l0,l1);
          }
        }
        c=MFMA(xh.s,f0fr,c); c=MFMA(xl.s,f0fr,c);
      }
      {
        const float gate=sigm(tcur*gc0+gbc0);
        const float tb=tcur*hbc0;
        #pragma unroll
        for(int r=0;r<4;++r){
          const int el=q*4+r;
          const float pre=c[r]*gate+tb;
          const float th=tanh_fast(pre);
          const unsigned u=__float_as_uint(th);
          hbh[0][el][jw]=(unsigned short)(u>>16);
          hbl[0][el][jw]=f2bf1(th-__uint_as_float(u&0xFFFF0000u));
          sb[0][el][jw]=f2bf1(gate*__builtin_fmaf(-th,th,1.f));
        }
      }
      __syncthreads();                       // B2

      // ---------- L1 ----------
      c=f32x4{bc1,bc1,bc1,bc1};
      #pragma unroll
      for(int kk=0;kk<2;++kk){
        const short8 ah=*reinterpret_cast<const short8*>(&hbh[0][m][kk*32+q*8]);
        const short8 al=*reinterpret_cast<const short8*>(&hbl[0][m][kk*32+q*8]);
        c=MFMA(ah,f1fr[kk],c); c=MFMA(al,f1fr[kk],c);
      }
      {
        const float gate=sigm(tcur*gc1+gbc1);
        const float tb=tcur*hbc1;
        #pragma unroll
        for(int r=0;r<4;++r){
          const int el=q*4+r;
          const float pre=c[r]*gate+tb;
          const float th=tanh_fast(pre);
          const unsigned u=__float_as_uint(th);
          hbh[1][el][jw]=(unsigned short)(u>>16);
          hbl[1][el][jw]=f2bf1(th-__uint_as_float(u&0xFFFF0000u));
          sb[1][el][jw]=f2bf1(gate*__builtin_fmaf(-th,th,1.f));
        }
      }
      __syncthreads();                       // B3

      // ---------- L2 ----------
      c=f32x4{bc2,bc2,bc2,bc2};
      #pragma unroll
      for(int kk=0;kk<2;++kk){
        const short8 ah=*reinterpret_cast<const short8*>(&hbh[1][m][kk*32+q*8]);
        const short8 al=*reinterpret_cast<const short8*>(&hbl[1][m][kk*32+q*8]);
        c=MFMA(ah,f2fr[kk],c); c=MFMA(al,f2fr[kk],c);
      }
      {
        const float gate=sigm(tcur*gc2+gbc2);
        const float tb=tcur*hbc2;
        #pragma unroll
        for(int r=0;r<4;++r){
          const int el=q*4+r;
          const float pre=c[r]*gate+tb;
          const float th=tanh_fast(pre);
          const unsigned u=__float_as_uint(th);
          hbh[0][el][jw]=(unsigned short)(u>>16);
          hbl[0][el][jw]=f2bf1(th-__uint_as_float(u&0xFFFF0000u));
          sb[2][el][jw]=f2bf1(gate*__builtin_fmaf(-th,th,1.f));
        }
      }
      __syncthreads();                       // B4

      // ---------- L3: dx ----------
      c=f32x4{bc3,bc3,bc3,bc3};
      #pragma unroll
      for(int kk=0;kk<2;++kk){
        const short8 ah=*reinterpret_cast<const short8*>(&hbh[0][m][kk*32+q*8]);
        const short8 al=*reinterpret_cast<const short8*>(&hbl[0][m][kk*32+q*8]);
        c=MFMA(ah,b3fr[kk],c); c=MFMA(al,b3fr[kk],c);
      }
      const float gate3=sigm(tcur*gc3+gbc3);
      {
        const float tb=tcur*hbc3;
        #pragma unroll
        for(int r=0;r<4;++r)
          dxw[wv][q*4+r][m]=c[r]*gate3+tb;
        if(q==0) sig3w[wv][m]=gate3;
      }
      WV();
      const float dxk=dxw[wv][e][a];
      dvp += fs*0.5f*dxk*dxk;                // deferred ||dx||^2 partial

      // ---------- trace factors (once per stage) ----------
      float tf[4][4];
      {
        const float4 sg4=*reinterpret_cast<const float4*>(&sig3w[wv][q*4]);
        #pragma unroll
        for(int r=0;r<4;++r){
          const ushort4 w4=*reinterpret_cast<const ushort4*>(&w3t[q*4+r][4*m]);
          const float sg=(&sg4.x)[r];
          tf[r][0]=sg*bfs(w4.x); tf[r][1]=sg*bfs(w4.y);
          tf[r][2]=sg*bfs(w4.z); tf[r][3]=sg*bfs(w4.w);
        }
      }

      // ---------- tangent per element ----------
      #pragma unroll
      for(int el=0; el<4; ++el){
        const int ee=wv*4+el;
        Frag a0[2];
        #pragma unroll
        for(int kk=0;kk<2;++kk){
          const uint4v wd=*reinterpret_cast<const uint4v*>(&w0b[m][kk*32+q*8]);
          const uint4v sd=*reinterpret_cast<const uint4v*>(&sb[0][ee][kk*32+q*8]);
          #pragma unroll
          for(int d=0;d<4;++d){
            const unsigned w2d=wd[d], s2d=sd[d];
            const float wlo=__uint_as_float(w2d<<16), whi=__uint_as_float(w2d&0xFFFF0000u);
            const float slo=__uint_as_float(s2d<<16), shi=__uint_as_float(s2d&0xFFFF0000u);
            a0[kk].d[d]=pk2bf(wlo*slo,whi*shi);
          }
        }
        f32x4 c1[4]={{0,0,0,0},{0,0,0,0},{0,0,0,0},{0,0,0,0}};
        #pragma unroll
        for(int kk=0;kk<2;++kk){
          #pragma unroll
          for(int nt=0;nt<4;++nt)
            c1[nt]=MFMA(a0[kk].s,b1fr[kk][nt],c1[nt]);   // cols 4m+nt
        }
        // scale by s1 (b64 read) and store packed b64 -> vt in TRUE col order
        {
          const ushort4 s1v=*reinterpret_cast<const ushort4*>(&sb[1][ee][4*m]);
          const float sc0=bfs(s1v.x),sc1=bfs(s1v.y),sc2=bfs(s1v.z),sc3=bfs(s1v.w);
          #pragma unroll
          for(int r=0;r<4;++r){
            uint2 dw;
            dw.x=pk2bf(c1[0][r]*sc0, c1[1][r]*sc1);
            dw.y=pk2bf(c1[2][r]*sc2, c1[3][r]*sc3);
            *reinterpret_cast<uint2*>(&vt[wv][q*4+r][4*m])=dw;
          }
        }
        WV();
        short8 a2[2];
        #pragma unroll
        for(int kk=0;kk<2;++kk)
          a2[kk]=*reinterpret_cast<const short8*>(&vt[wv][m][kk*32+q*8]);
        f32x4 c2[4]={{0,0,0,0},{0,0,0,0},{0,0,0,0},{0,0,0,0}};
        #pragma unroll
        for(int kk=0;kk<2;++kk){
          #pragma unroll
          for(int nt=0;nt<4;++nt)
            c2[nt]=MFMA(a2[kk],b2fr[kk][nt],c2[nt]);     // cols 4m+nt
        }
        // trace partial: sum_{r,nt} c2[nt][r]*s2[4m+nt]*tf[r][nt]
        {
          const ushort4 s2v=*reinterpret_cast<const ushort4*>(&sb[2][ee][4*m]);
          const float s20=bfs(s2v.x),s21=bfs(s2v.y),s22=bfs(s2v.z),s23=bfs(s2v.w);
          float tr;
          {
            float d0=c2[0][0]*tf[0][0]+c2[0][1]*tf[1][0]+c2[0][2]*tf[2][0]+c2[0][3]*tf[3][0];
            float d1=c2[1][0]*tf[0][1]+c2[1][1]*tf[1][1]+c2[1][2]*tf[2][1]+c2[1][3]*tf[3][1];
            float d2=c2[2][0]*tf[0][2]+c2[2][1]*tf[1][2]+c2[2][2]*tf[2][2]+c2[2][3]*tf[3][2];
            float d3=c2[3][0]*tf[0][3]+c2[3][1]*tf[1][3]+c2[3][2]*tf[2][3]+c2[3][3]*tf[3][3];
            tr=d0*s20+d1*s21+d2*s22+d3*s23;
          }
          trp[el] += fs*tr;                  // deferred: reduce at kernel end
        }
        WV();
      }

      // ---------- RK4 state update ----------
      dzx += fs*dxk;
      const float cn=(stage==2)?1.f:0.5f;
      if(stage<3) zwx=zbx+cn*hs*dxk;
    }
    zbx += dzx;
    p.out[(step+1)*(NB*DD)+b*DD+a]=zbx;
  }

  // ---------- deferred reductions ----------
  #pragma unroll
  for(int el=0; el<4; ++el){
    float v=trp[el];
    #pragma unroll
    for(int mk=32;mk>=1;mk>>=1) v+=__shfl_xor(v,mk,64);
    if(lane==el) p.out[3*NB*DD + blockIdx.x*EPB + wv*4 + el]=v;
  }
  {
    float v=dvp;
    #pragma unroll
    for(int mk=8;mk>=1;mk>>=1) v+=__shfl_xor(v,mk,16);
    if(a==0){
      p.out[3*NB*DD+NB+b]=fabsf(v);
      p.out[3*NB*DD+2*NB+b]=0.f;
    }
  }
}

extern "C" void kernel_launch(void* const* d_in, const int* in_sizes, int n_in,
                              void* d_out, int out_size, void* d_ws, size_t ws_size,
                              hipStream_t stream){
  Params p;
  p.ts  = (const float*)d_in[0];
  p.x0  = (const float*)d_in[1];
  p.W0  = (const float*)d_in[2];  p.b0 =(const float*)d_in[3];
  p.g0  = (const float*)d_in[4];  p.gb0=(const float*)d_in[5];  p.hb0=(const float*)d_in[6];
  p.W1  = (const float*)d_in[7];  p.b1 =(const float*)d_in[8];
  p.g1  = (const float*)d_in[9];  p.gb1=(const float*)d_in[10]; p.hb1=(const float*)d_in[11];
  p.W2  = (const float*)d_in[12]; p.b2 =(const float*)d_in[13];
  p.g2  = (const float*)d_in[14]; p.gb2=(const float*)d_in[15]; p.hb2=(const float*)d_in[16];
  p.W3  = (const float*)d_in[17]; p.b3 =(const float*)d_in[18];
  p.g3  = (const float*)d_in[19]; p.gb3=(const float*)d_in[20]; p.hb3=(const float*)d_in[21];
  p.out = (float*)d_out;
  hipLaunchKernelGGL(traj_kernel, dim3(NB/EPB), dim3(256), 0, stream, p);
}

// Round 5
// 253.367 us; speedup vs baseline: 35.9896x; 1.0493x over previous
//
#include <hip/hip_runtime.h>

#define NB 32768
#define DD 16
#define HH 64
#define EPB 16

typedef __attribute__((ext_vector_type(8))) short short8;
typedef __attribute__((ext_vector_type(4))) float f32x4;
typedef __attribute__((ext_vector_type(4))) unsigned uint4v;

union Frag { short8 s; uint4v u; unsigned d[4]; };

struct Params {
  const float *ts, *x0;
  const float *W0,*b0,*g0,*gb0,*hb0;
  const float *W1,*b1,*g1,*gb1,*hb1;
  const float *W2,*b2,*g2,*gb2,*hb2;
  const float *W3,*b3,*g3,*gb3,*hb3;
  float *out;
};

__device__ __forceinline__ float bfs(unsigned short u){
  return __uint_as_float(((unsigned)u)<<16);
}
__device__ __forceinline__ unsigned short f2bf(float f){   // full RNE (init only)
  unsigned u=__float_as_uint(f);
  return (unsigned short)((u + 0x7FFFu + ((u>>16)&1u))>>16);
}
// round-to-nearest bf16 pair, packed: 3 ops / 2 values
__device__ __forceinline__ unsigned pk2bf(float lo, float hi){
  unsigned a=__float_as_uint(lo)+0x8000u;
  unsigned b=__float_as_uint(hi)+0x8000u;
  return __builtin_amdgcn_perm(b, a, 0x07060302u);
}
__device__ __forceinline__ unsigned short f2bf1(float f){
  return (unsigned short)((__float_as_uint(f)+0x8000u)>>16);   // shr folds into d16_hi store
}
__device__ __forceinline__ float sigm(float u){
  return __builtin_amdgcn_rcpf(1.0f+__builtin_amdgcn_exp2f(-1.44269504f*u));
}
#define WV() __builtin_amdgcn_wave_barrier()
#define MFMA(A,B,C) __builtin_amdgcn_mfma_f32_16x16x32_bf16((A),(B),(C),0,0,0)

// gated-tanh epilogue: th = 1-2r, r = 1/(1+e^{2 pre});  s = gate*(1-th^2) = 4 gate r (1-r)
__device__ __forceinline__ void fwd_epi(const f32x4& c, float tcur,
    float gc, float gbc, float hbc,
    unsigned short* __restrict__ hdst, unsigned short* __restrict__ sdst,
    int jw, int q)
{
  const float gate = sigm(tcur*gc+gbc);
  const float gk   = gate*2.88539008f;       // 2*log2(e)*gate
  const float tbk  = (tcur*hbc)*2.88539008f;
  const float g4   = 4.0f*gate;
  #pragma unroll
  for(int r=0;r<4;++r){
    const int el=q*4+r;
    const float preK = c[r]*gk + tbk;
    const float e    = __builtin_amdgcn_exp2f(preK);
    const float rc   = __builtin_amdgcn_rcpf(1.0f+e);
    const float th   = __builtin_fmaf(-2.0f,rc,1.0f);
    hdst[el*72+jw] = f2bf1(th);
    const float sv   = (g4*rc)*(1.0f-rc);
    sdst[el*72+jw] = f2bf1(sv);
  }
}

__global__ __launch_bounds__(256,2) void traj_kernel(Params p){
  __shared__ __align__(16) unsigned short w0b[DD][72];     // W0[a][i]
  __shared__ __align__(16) unsigned short w3t[DD][72];     // W3^T[a][j]
  __shared__ __align__(16) float xbuf[DD][20];
  __shared__ __align__(16) unsigned short hbh[2][EPB][72]; // bf16 activations (ping-pong)
  __shared__ __align__(16) unsigned short sb[3][EPB][72];  // s0,s1,s2
  __shared__ float dxw[4][EPB][17];
  __shared__ __align__(16) float sig3w[4][DD];
  __shared__ __align__(16) unsigned short vt[4][DD][72];   // per-wave V1

  const int tid = threadIdx.x;
  const int e   = tid>>4;
  const int a   = tid&15;
  const int wv  = tid>>6;
  const int lane= tid&63;
  const int m   = lane&15;
  const int q   = lane>>4;
  const int b   = blockIdx.x*EPB + e;
  const int jw  = wv*16 + m;     // forward output column of this lane

  // ---- persistent register weight fragments ----
  short8 f0fr, f1fr[2], f2fr[2], b3fr[2];
  short8 b1fr[2][4], b2fr[2][4];   // tangent, N-permuted: cols 4m+nt
  {
    #pragma unroll
    for(int j=0;j<8;++j){
      const int k=q*8+j;
      f0fr[j]=(k<DD)?(short)f2bf(p.W0[k*HH+jw]):(short)0;
    }
    #pragma unroll
    for(int kk=0;kk<2;++kk){
      #pragma unroll
      for(int j=0;j<8;++j){
        const int k=kk*32+q*8+j;
        f1fr[kk][j]=(short)f2bf(p.W1[k*HH+jw]);
        f2fr[kk][j]=(short)f2bf(p.W2[k*HH+jw]);
        b3fr[kk][j]=(short)f2bf(p.W3[k*DD+m]);
      }
      #pragma unroll
      for(int nt=0;nt<4;++nt){
        #pragma unroll
        for(int j=0;j<8;++j){
          const int k=kk*32+q*8+j;
          b1fr[kk][nt][j]=(short)f2bf(p.W1[k*HH+4*m+nt]);
          b2fr[kk][nt][j]=(short)f2bf(p.W2[k*HH+4*m+nt]);
        }
      }
    }
  }
  const float bc0=p.b0[jw], gc0=p.g0[jw], gbc0=p.gb0[jw], hbc0=p.hb0[jw];
  const float bc1=p.b1[jw], gc1=p.g1[jw], gbc1=p.gb1[jw], hbc1=p.hb1[jw];
  const float bc2=p.b2[jw], gc2=p.g2[jw], gbc2=p.gb2[jw], hbc2=p.hb2[jw];
  const float bc3=p.b3[m],  gc3=p.g3[m],  gbc3=p.gb3[m],  hbc3=p.hb3[m];

  for(int idx=tid; idx<DD*HH; idx+=256) w0b[idx>>6][idx&63]=f2bf(p.W0[idx]);
  for(int idx=tid; idx<HH*DD; idx+=256) w3t[idx&15][idx>>4]=f2bf(p.W3[idx]);
  __syncthreads();

  float zbx = p.x0[b*DD+a];
  p.out[b*DD+a]=zbx;
  float trp[4]={0.f,0.f,0.f,0.f};
  float dvp=0.f;

  #pragma unroll 1
  for(int step=0; step<2; ++step){
    const float t0=p.ts[step], t1=p.ts[step+1];
    const float hs=t1-t0;
    float dzx=0.f;
    float zwx=zbx;
    #pragma unroll 1
    for(int stage=0; stage<4; ++stage){
      const float cin=(stage==0)?0.f:((stage==3)?1.f:0.5f);
      const float tcur=t0+cin*hs;
      const float wg=(stage==0||stage==3)?1.f:2.f;
      const float fs=hs*(1.f/6.f)*wg;
      const float fs5=0.5f*fs;

      xbuf[e][a]=zwx;
      __syncthreads();                       // B1

      // ---------- L0: X @ W0 (hi/lo split for fp32 state) ----------
      f32x4 c={bc0,bc0,bc0,bc0};
      {
        Frag xh, xl; xh.s=short8{0,0,0,0,0,0,0,0}; xl.s=xh.s;
        if(q<2){
          const float4 xa=*reinterpret_cast<const float4*>(&xbuf[m][q*8]);
          const float4 xb=*reinterpret_cast<const float4*>(&xbuf[m][q*8+4]);
          const float xv[8]={xa.x,xa.y,xa.z,xa.w,xb.x,xb.y,xb.z,xb.w};
          #pragma unroll
          for(int d=0;d<4;++d){
            const unsigned u0=__float_as_uint(xv[2*d]), u1=__float_as_uint(xv[2*d+1]);
            xh.d[d]=__builtin_amdgcn_perm(u1,u0,0x07060302u);
            const float l0=xv[2*d]-__uint_as_float(u0&0xFFFF0000u);
            const float l1=xv[2*d+1]-__uint_as_float(u1&0xFFFF0000u);
            xl.d[d]=pk2bf(l0,l1);
          }
        }
        c=MFMA(xh.s,f0fr,c); c=MFMA(xl.s,f0fr,c);
      }
      fwd_epi(c,tcur,gc0,gbc0,hbc0,&hbh[0][0][0],&sb[0][0][0],jw,q);
      __syncthreads();                       // B2

      // ---------- L1 ----------
      c=f32x4{bc1,bc1,bc1,bc1};
      #pragma unroll
      for(int kk=0;kk<2;++kk){
        const short8 ah=*reinterpret_cast<const short8*>(&hbh[0][m][kk*32+q*8]);
        c=MFMA(ah,f1fr[kk],c);
      }
      fwd_epi(c,tcur,gc1,gbc1,hbc1,&hbh[1][0][0],&sb[1][0][0],jw,q);
      __syncthreads();                       // B3

      // ---------- L2 ----------
      c=f32x4{bc2,bc2,bc2,bc2};
      #pragma unroll
      for(int kk=0;kk<2;++kk){
        const short8 ah=*reinterpret_cast<const short8*>(&hbh[1][m][kk*32+q*8]);
        c=MFMA(ah,f2fr[kk],c);
      }
      fwd_epi(c,tcur,gc2,gbc2,hbc2,&hbh[0][0][0],&sb[2][0][0],jw,q);  // h2 -> buf0
      __syncthreads();                       // B4

      // ---------- L3: dx ----------
      c=f32x4{bc3,bc3,bc3,bc3};
      #pragma unroll
      for(int kk=0;kk<2;++kk){
        const short8 ah=*reinterpret_cast<const short8*>(&hbh[0][m][kk*32+q*8]);
        c=MFMA(ah,b3fr[kk],c);
      }
      const float gate3=sigm(tcur*gc3+gbc3);
      {
        const float tb=tcur*hbc3;
        #pragma unroll
        for(int r=0;r<4;++r)
          dxw[wv][q*4+r][m]=c[r]*gate3+tb;
        if(q==0) sig3w[wv][m]=gate3;
      }
      WV();
      const float dxk=dxw[wv][e][a];
      dvp += fs5*dxk*dxk;

      // ---------- trace factors (once per stage) ----------
      float tf[4][4];
      {
        const float4 sg4=*reinterpret_cast<const float4*>(&sig3w[wv][q*4]);
        #pragma unroll
        for(int r=0;r<4;++r){
          const ushort4 w4=*reinterpret_cast<const ushort4*>(&w3t[q*4+r][4*m]);
          const float sg=(&sg4.x)[r];
          tf[r][0]=sg*bfs(w4.x); tf[r][1]=sg*bfs(w4.y);
          tf[r][2]=sg*bfs(w4.z); tf[r][3]=sg*bfs(w4.w);
        }
      }

      // ---------- tangent per element ----------
      #pragma unroll
      for(int el=0; el<4; ++el){
        const int ee=wv*4+el;
        Frag a0[2];
        #pragma unroll
        for(int kk=0;kk<2;++kk){
          const uint4v wd=*reinterpret_cast<const uint4v*>(&w0b[m][kk*32+q*8]);
          const uint4v sd=*reinterpret_cast<const uint4v*>(&sb[0][ee][kk*32+q*8]);
          #pragma unroll
          for(int d=0;d<4;++d){
            const unsigned w2d=wd[d], s2d=sd[d];
            const float wlo=__uint_as_float(w2d<<16), whi=__uint_as_float(w2d&0xFFFF0000u);
            const float slo=__uint_as_float(s2d<<16), shi=__uint_as_float(s2d&0xFFFF0000u);
            a0[kk].d[d]=pk2bf(wlo*slo,whi*shi);
          }
        }
        f32x4 c1[4]={{0,0,0,0},{0,0,0,0},{0,0,0,0},{0,0,0,0}};
        #pragma unroll
        for(int kk=0;kk<2;++kk){
          #pragma unroll
          for(int nt=0;nt<4;++nt)
            c1[nt]=MFMA(a0[kk].s,b1fr[kk][nt],c1[nt]);   // cols 4m+nt
        }
        {
          const ushort4 s1v=*reinterpret_cast<const ushort4*>(&sb[1][ee][4*m]);
          const float sc0=bfs(s1v.x),sc1=bfs(s1v.y),sc2=bfs(s1v.z),sc3=bfs(s1v.w);
          #pragma unroll
          for(int r=0;r<4;++r){
            uint2 dw;
            dw.x=pk2bf(c1[0][r]*sc0, c1[1][r]*sc1);
            dw.y=pk2bf(c1[2][r]*sc2, c1[3][r]*sc3);
            *reinterpret_cast<uint2*>(&vt[wv][q*4+r][4*m])=dw;
          }
        }
        WV();
        short8 a2[2];
        #pragma unroll
        for(int kk=0;kk<2;++kk)
          a2[kk]=*reinterpret_cast<const short8*>(&vt[wv][m][kk*32+q*8]);
        f32x4 c2[4]={{0,0,0,0},{0,0,0,0},{0,0,0,0},{0,0,0,0}};
        #pragma unroll
        for(int kk=0;kk<2;++kk){
          #pragma unroll
          for(int nt=0;nt<4;++nt)
            c2[nt]=MFMA(a2[kk],b2fr[kk][nt],c2[nt]);     // cols 4m+nt
        }
        {
          const ushort4 s2v=*reinterpret_cast<const ushort4*>(&sb[2][ee][4*m]);
          const float s20=bfs(s2v.x),s21=bfs(s2v.y),s22=bfs(s2v.z),s23=bfs(s2v.w);
          float d0=c2[0][0]*tf[0][0]+c2[0][1]*tf[1][0]+c2[0][2]*tf[2][0]+c2[0][3]*tf[3][0];
          float d1=c2[1][0]*tf[0][1]+c2[1][1]*tf[1][1]+c2[1][2]*tf[2][1]+c2[1][3]*tf[3][1];
          float d2=c2[2][0]*tf[0][2]+c2[2][1]*tf[1][2]+c2[2][2]*tf[2][2]+c2[2][3]*tf[3][2];
          float d3=c2[3][0]*tf[0][3]+c2[3][1]*tf[1][3]+c2[3][2]*tf[2][3]+c2[3][3]*tf[3][3];
          const float tr=d0*s20+d1*s21+d2*s22+d3*s23;
          trp[el] += fs*tr;
        }
        WV();
      }

      // ---------- RK4 state update ----------
      dzx += fs*dxk;
      const float cn=(stage==2)?1.f:0.5f;
      if(stage<3) zwx=zbx+cn*hs*dxk;
    }
    zbx += dzx;
    p.out[(step+1)*(NB*DD)+b*DD+a]=zbx;
  }

  // ---------- deferred reductions ----------
  #pragma unroll
  for(int el=0; el<4; ++el){
    float v=trp[el];
    #pragma unroll
    for(int mk=32;mk>=1;mk>>=1) v+=__shfl_xor(v,mk,64);
    if(lane==el) p.out[3*NB*DD + blockIdx.x*EPB + wv*4 + el]=v;
  }
  {
    float v=dvp;
    #pragma unroll
    for(int mk=8;mk>=1;mk>>=1) v+=__shfl_xor(v,mk,16);
    if(a==0){
      p.out[3*NB*DD+NB+b]=fabsf(v);
      p.out[3*NB*DD+2*NB+b]=0.f;
    }
  }
}

extern "C" void kernel_launch(void* const* d_in, const int* in_sizes, int n_in,
                              void* d_out, int out_size, void* d_ws, size_t ws_size,
                              hipStream_t stream){
  Params p;
  p.ts  = (const float*)d_in[0];
  p.x0  = (const float*)d_in[1];
  p.W0  = (const float*)d_in[2];  p.b0 =(const float*)d_in[3];
  p.g0  = (const float*)d_in[4];  p.gb0=(const float*)d_in[5];  p.hb0=(const float*)d_in[6];
  p.W1  = (const float*)d_in[7];  p.b1 =(const float*)d_in[8];
  p.g1  = (const float*)d_in[9];  p.gb1=(const float*)d_in[10]; p.hb1=(const float*)d_in[11];
  p.W2  = (const float*)d_in[12]; p.b2 =(const float*)d_in[13];
  p.g2  = (const float*)d_in[14]; p.gb2=(const float*)d_in[15]; p.hb2=(const float*)d_in[16];
  p.W3  = (const float*)d_in[17]; p.b3 =(const float*)d_in[18];
  p.g3  = (const float*)d_in[19]; p.gb3=(const float*)d_in[20]; p.hb3=(const float*)d_in[21];
  p.out = (float*)d_out;
  hipLaunchKernelGGL(traj_kernel, dim3(NB/EPB), dim3(256), 0, stream, p);
}